// Round 17
// baseline (293.752 us; speedup 1.0000x reference)
//
#include <hip/hip_runtime.h>
#include <stdint.h>

// Problem constants: T=2048, B=4, E=1024, H=16, D=64, M=T*B=8192
// q pre-scale: SCALING * log2(e) so scores are already in log2 domain
#define QSCALE 0.18033688011112042f

typedef unsigned short u16;
typedef unsigned int u32;
typedef unsigned long long u64;
typedef _Float16 f16;
typedef __attribute__((ext_vector_type(2))) __fp16 h16x2;   // builtin-compatible
typedef __attribute__((ext_vector_type(8))) _Float16 f16x8;
typedef __attribute__((ext_vector_type(8))) __bf16 bf16x8;
typedef __attribute__((ext_vector_type(4))) float f32x4;
typedef __attribute__((ext_vector_type(16))) float f32x16;
typedef __attribute__((ext_vector_type(8))) u16 u16x8;
typedef __attribute__((ext_vector_type(4))) u32 u32x4;

__device__ __forceinline__ void gl_lds16(const void* g, void* l) {
  __builtin_amdgcn_global_load_lds(
      (const __attribute__((address_space(1))) void*)g,
      (__attribute__((address_space(3))) void*)l, 16, 0, 0);
}

__device__ __forceinline__ u16 f2bf(float f) {
  unsigned int u = __float_as_uint(f);
  u += 0x7FFFu + ((u >> 16) & 1u);
  return (u16)(u >> 16);
}

// -------- f32 -> bf16 convert (all three inputs) + mask bitmap, one launch --
extern "C" __global__ __launch_bounds__(256) void cvt_all(
    const float* __restrict__ query, const float* __restrict__ w_in,
    const float* __restrict__ w_out, u16* __restrict__ dst,
    const unsigned char* __restrict__ mask, u64* __restrict__ mbits) {
  if (blockIdx.x == 12288) {
    const int i = threadIdx.x;
    if (i < 128) {
      const unsigned char* p = mask + i * 64;
      u64 bits = 0;
#pragma unroll
      for (int j = 0; j < 8; ++j) {
        const u64 c = *(const u64*)(p + j * 8);
#pragma unroll
        for (int bb = 0; bb < 8; ++bb)
          if ((c >> (8 * bb)) & 0xFFull) bits |= 1ull << (j * 8 + bb);
      }
      mbits[i] = bits;
    }
    return;
  }
  int i = (blockIdx.x * 256 + threadIdx.x) * 4;
  const float* src;
  int off;
  if (i < 8388608) {
    src = query; off = i;
  } else if (i < 11534336) {
    src = w_in; off = i - 8388608;
  } else {
    src = w_out; off = i - 11534336;
  }
  float4 v = *(const float4*)(src + off);
  ushort4 o;
  o.x = f2bf(v.x); o.y = f2bf(v.y); o.z = f2bf(v.z); o.w = f2bf(v.w);
  *(ushort4*)(dst + i) = o;
}

// ---------------- QKV projection GEMM (128x128, 2-buf, 1-ahead) ------------
extern "C" __global__ __launch_bounds__(256) void gemm_qkv(
    const u16* __restrict__ X, const u16* __restrict__ W,
    const float* __restrict__ bias,
    u16* __restrict__ qb, u16* __restrict__ kb, u16* __restrict__ vtb) {
  const int tid = threadIdx.x;
  const int w = tid >> 6, lane = tid & 63;
  const int lg = lane >> 4, ll = lane & 15;
  const int wm = w >> 1, wn = w & 1;

  const int xcd = blockIdx.x & 7;
  const int i6 = blockIdx.x >> 3;        // 0..191
  const int tx = xcd * 8 + (i6 & 7);     // 0..63
  const int ty = i6 >> 3;                // 0..23
  const int row0A = tx * 128;
  const int row0B = ty * 128;

  __shared__ __align__(16) u16 SM[16384];  // 32 KB: staging dbuf, then epilogue
  u16* Asb = SM;
  u16* Bsb = SM + 8192;

  f32x4 acc[4][4] = {};

  const int r_st = tid >> 2;
  const int cb_st = (tid & 3) * 16;

#pragma unroll
  for (int it = 0; it < 2; ++it) {
    gl_lds16((const char*)X + ((size_t)(row0A + it * 64 + r_st) * 1024) * 2 + cb_st,
             (char*)Asb + it * 4096 + w * 1024);
    gl_lds16((const char*)W + ((size_t)(row0B + it * 64 + r_st) * 1024) * 2 + cb_st,
             (char*)Bsb + it * 4096 + w * 1024);
  }

  for (int kt = 0; kt < 32; ++kt) {
    const int cur = kt & 1;
    asm volatile("s_waitcnt vmcnt(0)" ::: "memory");
    __syncthreads();
    if (kt + 1 < 32) {
      const int k0 = (kt + 1) * 32;
      const int nxt = cur ^ 1;
#pragma unroll
      for (int it = 0; it < 2; ++it) {
        gl_lds16((const char*)X + ((size_t)(row0A + it * 64 + r_st) * 1024 + k0) * 2 + cb_st,
                 (char*)(Asb + nxt * 4096) + it * 4096 + w * 1024);
        gl_lds16((const char*)W + ((size_t)(row0B + it * 64 + r_st) * 1024 + k0) * 2 + cb_st,
                 (char*)(Bsb + nxt * 4096) + it * 4096 + w * 1024);
      }
    }
    const u16* Ab = Asb + cur * 4096;
    const u16* Bb = Bsb + cur * 4096;
    const int kc = lg * 8;
    bf16x8 a[4], bfr[4];
#pragma unroll
    for (int i = 0; i < 4; ++i)
      a[i] = *(const bf16x8*)(Ab + (wm * 64 + i * 16 + ll) * 32 + kc);
#pragma unroll
    for (int j = 0; j < 4; ++j)
      bfr[j] = *(const bf16x8*)(Bb + (wn * 64 + j * 16 + ll) * 32 + kc);
#pragma unroll
    for (int i = 0; i < 4; ++i)
#pragma unroll
      for (int j = 0; j < 4; ++j)
        acc[i][j] = __builtin_amdgcn_mfma_f32_16x16x32_bf16(a[i], bfr[j], acc[i][j], 0, 0, 0);
  }

  // ---- epilogue: bias+convert -> LDS bounce (XOR-swz 16B slots)
  __syncthreads();
  const int which = row0B >> 10;  // 0=q 1=k 2=v
  const float scl = which == 0 ? QSCALE : 1.0f;
  const int hh0 = (row0B & 1023) >> 6;

#pragma unroll
  for (int j = 0; j < 4; ++j) {
    const int n = row0B + wn * 64 + j * 16 + ll;
    const float bv = bias[n];
#pragma unroll
    for (int i = 0; i < 4; ++i)
#pragma unroll
      for (int r = 0; r < 4; ++r) {
        const float val = (acc[i][j][r] + bv) * scl;
        u16 pay;
        if (which == 2) {
          const f16 hv = (f16)val;
          pay = __builtin_bit_cast(u16, hv);
        } else {
          pay = f2bf(val);
        }
        const int lrow = wn * 128 + r * 32 + wm * 16 + i * 4 + lg;
        const int slot = (j * 2 + (ll >> 3)) ^ (lrow & 7);
        SM[lrow * 64 + slot * 8 + (ll & 7)] = pay;
      }
  }
  __syncthreads();

  if (which < 2) {
    u16* dst = which ? kb : qb;
    const int lrow = tid;
    const int hh = hh0 + (lrow >> 7);
    const int bb = (lrow >> 5) & 3;
    const int tt = (row0A >> 2) + (lrow & 31);
    u16* gp = dst + ((size_t)(bb * 16 + hh) * 2048 + tt) * 64;
#pragma unroll
    for (int s = 0; s < 8; ++s)
      *(u16x8*)(gp + s * 8) = *(const u16x8*)(SM + lrow * 64 + ((s ^ (lrow & 7)) << 3));
  } else {
#pragma unroll
    for (int u = 0; u < 2; ++u) {
      const int rid = u * 256 + tid;
      const int bb = rid >> 7, hhr = (rid >> 6) & 1, dd = rid & 63;
      const int hh = hh0 + hhr;
      const int slot0 = dd >> 3, de = dd & 7;
      u16 col[32];
#pragma unroll
      for (int t2 = 0; t2 < 32; ++t2) {
        const int lrow = hhr * 128 + bb * 32 + t2;
        col[t2] = SM[lrow * 64 + ((slot0 ^ (lrow & 7)) << 3) + de];
      }
      u16* gp = vtb + ((size_t)(bb * 16 + hh) * 64 + dd) * 2048 + (row0A >> 2);
#pragma unroll
      for (int sg = 0; sg < 4; ++sg)
        *(u16x8*)(gp + sg * 8) = *(const u16x8*)(col + sg * 8);
    }
  }
}

// ---------------- flash attention fwd (v6: f16 P, dot2 lsum) ----------------
extern "C" __global__ __launch_bounds__(256, 4) void flash_fwd(
    const u16* __restrict__ q, const u16* __restrict__ k,
    const u16* __restrict__ vt, const u64* __restrict__ mbits,
    u16* __restrict__ attn_pre, float* __restrict__ stat_il) {
  const int lb = ((blockIdx.x & 7) << 7) + (blockIdx.x >> 3);
  const int bh = lb >> 4, tt = lb & 15;
  const int b = bh >> 4, hd = bh & 15;
  const int t0 = tt * 128;
  const int tid = threadIdx.x, w = tid >> 6, lane = tid & 63;
  const int hl = lane >> 5;  // lane half (0/1)
  const int l31 = lane & 31;

  __shared__ __align__(16) u16 Ks[2][64 * 64];  // 16 KB bf16
  __shared__ __align__(16) u16 Vs[2][64 * 64];  // 16 KB f16

  const int qrow = t0 + w * 32 + l31;
  const u16* qp = q + ((size_t)bh * 2048 + qrow) * 64 + hl * 8;
  bf16x8 qreg[4];
#pragma unroll
  for (int kg = 0; kg < 4; ++kg) qreg[kg] = *(const bf16x8*)(qp + kg * 16);

  f32x16 po[2] = {};
  float ls0 = 0.f, ls1 = 0.f;
  const h16x2 ones = {(__fp16)1.0f, (__fp16)1.0f};

  const int slot_r = tid >> 3;
  const int slot_c8 = (tid & 7) ^ (slot_r & 7);

#define STAGE_F(buf, s0_)                                                      \
  do {                                                                         \
    _Pragma("unroll") for (int it2 = 0; it2 < 2; ++it2) {                      \
      const int rr = it2 * 32 + slot_r;                                        \
      gl_lds16((const char*)k +                                                \
                   (((size_t)bh * 2048 + (s0_) + rr) * 64 + slot_c8 * 8) * 2,  \
               (char*)&Ks[buf][0] + it2 * 4096 + w * 1024);                    \
      gl_lds16((const char*)vt +                                               \
                   (((size_t)bh * 64 + rr) * 2048 + (s0_) + slot_c8 * 8) * 2,  \
               (char*)&Vs[buf][0] + it2 * 4096 + w * 1024);                    \
    }                                                                          \
  } while (0)

  STAGE_F(0, 0);
  asm volatile("s_waitcnt vmcnt(0)" ::: "memory");
  __builtin_amdgcn_s_barrier();

  for (int t = 0; t < 32; ++t) {
    const u64 mb = mbits[b * 32 + t];  // uniform -> SGPR
    const int cur = t & 1;
    if (t + 1 < 32) STAGE_F(cur ^ 1, (t + 1) * 64);

    const char* Kb = (const char*)&Ks[cur][0];
    const char* Vb = (const char*)&Vs[cur][0];

#pragma unroll
    for (int kt = 0; kt < 2; ++kt) {
      f32x16 z = {};
      const int key = kt * 32 + l31;
      __builtin_amdgcn_s_setprio(1);
#pragma unroll
      for (int kg = 0; kg < 4; ++kg) {
        const bf16x8 kf = *(const bf16x8*)(
            Kb + key * 128 + ((((kg << 1) | hl) ^ (key & 7)) << 4));
        z = __builtin_amdgcn_mfma_f32_32x32x16_bf16(kf, qreg[kg], z, 0, 0, 0);
      }
      __builtin_amdgcn_s_setprio(0);

      float ps[16];
#pragma unroll
      for (int r = 0; r < 16; ++r) ps[r] = __builtin_amdgcn_exp2f(z[r]);
      const u32 m32 = (u32)(mb >> (kt * 32));
      if (m32) {
#pragma unroll
        for (int r = 0; r < 16; ++r) {
          const int bitpos = (r & 3) + 8 * (r >> 2) + 4 * hl;
          if ((m32 >> bitpos) & 1u) ps[r] = 0.f;
        }
      }

      u32 w8[8];
#pragma unroll
      for (int j = 0; j < 8; ++j) {
        const h16x2 pk = __builtin_amdgcn_cvt_pkrtz(ps[2 * j], ps[2 * j + 1]);
        w8[j] = __builtin_bit_cast(u32, pk);
        if (j & 1)
          ls1 = __builtin_amdgcn_fdot2(pk, ones, ls1, false);
        else
          ls0 = __builtin_amdgcn_fdot2(pk, ones, ls0, false);
      }

#pragma unroll
      for (int f = 0; f < 2; ++f) {
        u32 d0 = w8[4 * f], d1 = w8[4 * f + 1];
        u32 s0w = w8[4 * f + 2], s1w = w8[4 * f + 3];
        asm volatile("v_permlane32_swap_b32 %0, %1" : "+v"(d0), "+v"(s0w));
        asm volatile("v_permlane32_swap_b32 %0, %1" : "+v"(d1), "+v"(s1w));
        const f16x8 pa = __builtin_bit_cast(f16x8, (u32x4){d0, d1, s0w, s1w});
        const int g = kt * 2 + f;
        __builtin_amdgcn_s_setprio(1);
#pragma unroll
        for (int dt = 0; dt < 2; ++dt) {
          const int d = dt * 32 + l31;
          const f16x8 vf = *(const f16x8*)(
              Vb + d * 128 + ((((g << 1) | hl) ^ (d & 7)) << 4));
          po[dt] = __builtin_amdgcn_mfma_f32_32x32x16_f16(pa, vf, po[dt], 0, 0, 0);
        }
        __builtin_amdgcn_s_setprio(0);
      }
    }

    asm volatile("s_waitcnt vmcnt(0)" ::: "memory");
    __builtin_amdgcn_s_barrier();
  }

  float lsum = ls0 + ls1;
  lsum += __shfl_xor(lsum, 32, 64);
  const float linv = 1.0f / lsum;
  if (lane < 32)
    stat_il[(size_t)bh * 2048 + t0 + w * 32 + lane] = linv;

#pragma unroll
  for (int r = 0; r < 16; ++r) {
    const int qi = (r & 3) + 8 * (r >> 2) + 4 * hl;
    const float lv = __shfl(linv, qi, 64);
    const int trow = t0 + w * 32 + qi;
#pragma unroll
    for (int dt = 0; dt < 2; ++dt) {
      const int dd = dt * 32 + l31;
      attn_pre[((size_t)(trow * 4 + b)) * 1024 + hd * 64 + dd] =
          f2bf(po[dt][r] * lv);
    }
  }
#undef STAGE_F
}

// ------- fused tail: wavg 128x128 (1024 blocks) + gemm_out (512), 2:1 ------
// wavg s-tile doubled to 128: Q-tile staged 16x instead of 32x per (b,tt)
// -> ~2x less Q re-read traffic. Shared 64KB LDS pool, 2 blocks/CU.
extern "C" __global__ __launch_bounds__(256, 2) void tail_fused(
    const u16* __restrict__ q, const u16* __restrict__ k,
    const u64* __restrict__ mbits, const float* __restrict__ stat_il,
    float* __restrict__ wout,
    const u16* __restrict__ A, const u16* __restrict__ Wo,
    const float* __restrict__ bias, float* __restrict__ out) {
  __shared__ __align__(16) u16 POOL[32768];  // 64 KB
  const int bid = blockIdx.x;     // 1536 = 512 groups of {2 wavg, 1 gemm_out}
  const int g3 = bid / 3, r3 = bid % 3;
  const int tid = threadIdx.x, w = tid >> 6, lane = tid & 63;

  if (r3 == 2) {
    // ================= gemm_out block g3 (0..511) =================
    const int lg = lane >> 4, ll = lane & 15;
    const int wm = w >> 1, wn = w & 1;
    const int xcd = g3 & 7;
    const int i6 = g3 >> 3;
    const int row0A = (xcd * 8 + (i6 & 7)) * 128;
    const int row0B = (i6 >> 3) * 128;

    u16* Asb = POOL;
    u16* Bsb = POOL + 8192;

    f32x4 acc[4][4] = {};
    const int r_st = tid >> 2;
    const int cb_st = (tid & 3) * 16;

#pragma unroll
    for (int it = 0; it < 2; ++it) {
      gl_lds16((const char*)A + ((size_t)(row0A + it * 64 + r_st) * 1024) * 2 + cb_st,
               (char*)Asb + it * 4096 + w * 1024);
      gl_lds16((const char*)Wo + ((size_t)(row0B + it * 64 + r_st) * 1024) * 2 + cb_st,
               (char*)Bsb + it * 4096 + w * 1024);
    }

    for (int kt = 0; kt < 32; ++kt) {
      const int cur = kt & 1;
      asm volatile("s_waitcnt vmcnt(0)" ::: "memory");
      __syncthreads();
      if (kt + 1 < 32) {
        const int k0 = (kt + 1) * 32;
        const int nxt = cur ^ 1;
#pragma unroll
        for (int it = 0; it < 2; ++it) {
          gl_lds16((const char*)A + ((size_t)(row0A + it * 64 + r_st) * 1024 + k0) * 2 + cb_st,
                   (char*)(Asb + nxt * 4096) + it * 4096 + w * 1024);
          gl_lds16((const char*)Wo + ((size_t)(row0B + it * 64 + r_st) * 1024 + k0) * 2 + cb_st,
                   (char*)(Bsb + nxt * 4096) + it * 4096 + w * 1024);
        }
      }
      const u16* Ab = Asb + cur * 4096;
      const u16* Bb = Bsb + cur * 4096;
      const int kc = lg * 8;
      bf16x8 a[4], bfr[4];
#pragma unroll
      for (int i = 0; i < 4; ++i)
        a[i] = *(const bf16x8*)(Ab + (wm * 64 + i * 16 + ll) * 32 + kc);
#pragma unroll
      for (int j = 0; j < 4; ++j)
        bfr[j] = *(const bf16x8*)(Bb + (wn * 64 + j * 16 + ll) * 32 + kc);
#pragma unroll
      for (int i = 0; i < 4; ++i)
#pragma unroll
        for (int j = 0; j < 4; ++j)
          acc[i][j] = __builtin_amdgcn_mfma_f32_16x16x32_bf16(a[i], bfr[j], acc[i][j], 0, 0, 0);
    }

#pragma unroll
    for (int j = 0; j < 4; ++j) {
      const int n = row0B + wn * 64 + j * 16 + ll;
      const float bv = bias[n];
#pragma unroll
      for (int i = 0; i < 4; ++i)
#pragma unroll
        for (int r = 0; r < 4; ++r) {
          const int m = row0A + wm * 64 + i * 16 + lg * 4 + r;
          out[(size_t)m * 1024 + n] = acc[i][j][r] + bv;
        }
    }
    return;
  }

  // ================= wavg block wb (0..1023), tile 128t x 128s ==========
  const int wb = g3 * 2 + r3;
  const int lb = ((wb & 7) << 7) + (wb >> 3);  // XCD-chunked swizzle
  const int b = lb >> 8, tt = (lb >> 4) & 15, sp = lb & 15;
  const int t0 = tt * 128, s0 = sp * 128;
  const int hl = lane >> 5;
  const int l31 = lane & 31;

  // Q[buf] at POOL + buf*8192 u16 (16 KB each); K[buf] at POOL+16384 + buf*8192
  const int slot_r8 = tid >> 3;
  const int slot_c8 = (tid & 7) ^ (slot_r8 & 7);

  // mask: two u64 words cover s0..s0+128
  u32 m32t[4];
  {
    const u64 mb0 = mbits[b * 32 + sp * 2];
    const u64 mb1 = mbits[b * 32 + sp * 2 + 1];
    m32t[0] = (u32)mb0; m32t[1] = (u32)(mb0 >> 32);
    m32t[2] = (u32)mb1; m32t[3] = (u32)(mb1 >> 32);
  }
  const bool domask = (m32t[0] | m32t[1] | m32t[2] | m32t[3]) != 0u;

#define STAGE_W(buf, hh)                                                       \
  do {                                                                         \
    const size_t qo_ = (size_t)(b * 16 + (hh)) * 2048;                         \
    _Pragma("unroll") for (int i2 = 0; i2 < 4; ++i2) {                         \
      const int rr = i2 * 32 + slot_r8;                                        \
      gl_lds16((const char*)q + ((qo_ + t0 + rr) * 64 + slot_c8 * 8) * 2,      \
               (char*)(POOL + (buf)*8192) + i2 * 4096 + w * 1024);             \
      gl_lds16((const char*)k + ((qo_ + s0 + rr) * 64 + slot_c8 * 8) * 2,      \
               (char*)(POOL + 16384 + (buf)*8192) + i2 * 4096 + w * 1024);     \
    }                                                                          \
  } while (0)

  STAGE_W(0, 0);
  asm volatile("s_waitcnt vmcnt(0)" ::: "memory");
  __syncthreads();

  float accw[64] = {};
  for (int h = 0; h < 16; ++h) {
    const int cur = h & 1;
    const float ilh =
        stat_il[(size_t)(b * 16 + h) * 2048 + t0 + w * 32 + l31];

    if (h + 1 < 16) STAGE_W(cur ^ 1, h + 1);

    const char* Qb = (const char*)(POOL + cur * 8192);
    const char* Kb = (const char*)(POOL + 16384 + cur * 8192);

    const int qr = w * 32 + l31;
    bf16x8 qf[4];
#pragma unroll
    for (int kg = 0; kg < 4; ++kg)
      qf[kg] = *(const bf16x8*)(
          Qb + qr * 128 + ((((kg << 1) | hl) ^ (qr & 7)) << 4));

#pragma unroll
    for (int kt = 0; kt < 4; ++kt) {
      f32x16 z = {};
      const int key = kt * 32 + l31;
      __builtin_amdgcn_s_setprio(1);
#pragma unroll
      for (int kg = 0; kg < 4; ++kg) {
        const bf16x8 kf = *(const bf16x8*)(
            Kb + key * 128 + ((((kg << 1) | hl) ^ (key & 7)) << 4));
        z = __builtin_amdgcn_mfma_f32_32x32x16_bf16(kf, qf[kg], z, 0, 0, 0);
      }
      __builtin_amdgcn_s_setprio(0);
#pragma unroll
      for (int r = 0; r < 16; ++r) {
        float p = __builtin_amdgcn_exp2f(z[r]);
        if (domask) {
          const int bitpos = (r & 3) + 8 * (r >> 2) + 4 * hl;
          if ((m32t[kt] >> bitpos) & 1u) p = 0.f;
        }
        accw[kt * 16 + r] = fmaf(p, ilh, accw[kt * 16 + r]);
      }
    }

    asm volatile("s_waitcnt vmcnt(0)" ::: "memory");
    __syncthreads();
  }

  // transpose via 64KB f32 LDS tile [128 t][128 s] (swizzled 16B slots)
  float* tb = (float*)POOL;
#pragma unroll
  for (int kt = 0; kt < 4; ++kt)
#pragma unroll
    for (int q8 = 0; q8 < 4; ++q8) {
      f32x4 qd;
#pragma unroll
      for (int e = 0; e < 4; ++e) qd[e] = accw[kt * 16 + q8 * 4 + e] * 0.0625f;
      const int row = w * 32 + l31;
      const int slot = kt * 8 + q8 * 2 + hl;  // 0..31 (16B units in 512B row)
      *(f32x4*)(tb + row * 128 + ((slot ^ (row & 7)) << 2)) = qd;
    }
  __syncthreads();
  {
    const int row = tid >> 1, h2 = tid & 1;
    float* gbase = wout + ((size_t)b * 2048 + t0 + row) * 2048 + s0;
#pragma unroll
    for (int u = 0; u < 16; ++u) {
      const int slot = h2 * 16 + u;
      const f32x4 v = *(const f32x4*)(tb + row * 128 + ((slot ^ (row & 7)) << 2));
      *(f32x4*)(gbase + slot * 4) = v;
    }
  }
#undef STAGE_W
}

extern "C" void kernel_launch(void* const* d_in, const int* in_sizes, int n_in,
                              void* d_out, int out_size, void* d_ws, size_t ws_size,
                              hipStream_t stream) {
  const float* query = (const float*)d_in[0];
  const unsigned char* mask = (const unsigned char*)d_in[1];
  const float* w_in = (const float*)d_in[2];
  const float* b_in = (const float*)d_in[3];
  const float* w_out = (const float*)d_in[4];
  const float* b_out = (const float*)d_in[5];

  float* out0 = (float*)d_out;                   // attn [T,B,E] = 8388608 f32
  float* outw = out0 + (size_t)8388608;          // attn_w_avg [B,T,S]

  char* ws = (char*)d_ws;
  u16* Xbf   = (u16*)(ws + 0);            // 16 MB  query bf16 [8192][1024]
  u16* Wqkv  = (u16*)(ws + 16777216);     // 6 MB   in_proj_weight bf16
  u16* Woutb = (u16*)(ws + 23068672);     // 2 MB   out_w bf16
  u16* qb    = (u16*)(ws + 25165824);     // 16 MB  q [B,H,T,D] bf16 (scaled)
  u16* kb    = (u16*)(ws + 41943040);     // 16 MB  k [B,H,T,D]
  u16* vtb   = (u16*)(ws + 75497472);     // 16 MB  v^T [B,H,D,T] f16
  u16* ap    = (u16*)(ws + 92274688);     // 16 MB  attn_pre bf16 [8192][1024]
  float* sil = (float*)(ws + 109051904);  // 0.5 MB row 1/l [B*H][T]
  u64* mbits = (u64*)(ws + 109576192);    // 1 KB   mask bitmap [B][32]

  cvt_all<<<12289, 256, 0, stream>>>(query, w_in, w_out, Xbf, mask, mbits);
  gemm_qkv<<<1536, 256, 0, stream>>>(Xbf, Wqkv, b_in, qb, kb, vtb);
  flash_fwd<<<1024, 256, 0, stream>>>(qb, kb, vtb, mbits, ap, sil);
  tail_fused<<<1536, 256, 0, stream>>>(qb, kb, mbits, sil, outw,
                                       ap, Woutb, b_out, out0);
}

// Round 18
// 269.104 us; speedup vs baseline: 1.0916x; 1.0916x over previous
//
#include <hip/hip_runtime.h>
#include <stdint.h>

// Problem constants: T=2048, B=4, E=1024, H=16, D=64, M=T*B=8192
// q pre-scale: SCALING * log2(e) so scores are already in log2 domain
#define QSCALE 0.18033688011112042f

typedef unsigned short u16;
typedef unsigned int u32;
typedef unsigned long long u64;
typedef _Float16 f16;
typedef __attribute__((ext_vector_type(2))) __fp16 h16x2;   // builtin-compatible
typedef __attribute__((ext_vector_type(8))) _Float16 f16x8;
typedef __attribute__((ext_vector_type(8))) __bf16 bf16x8;
typedef __attribute__((ext_vector_type(4))) float f32x4;
typedef __attribute__((ext_vector_type(16))) float f32x16;
typedef __attribute__((ext_vector_type(8))) u16 u16x8;
typedef __attribute__((ext_vector_type(4))) u32 u32x4;

__device__ __forceinline__ void gl_lds16(const void* g, void* l) {
  __builtin_amdgcn_global_load_lds(
      (const __attribute__((address_space(1))) void*)g,
      (__attribute__((address_space(3))) void*)l, 16, 0, 0);
}

__device__ __forceinline__ u16 f2bf(float f) {
  unsigned int u = __float_as_uint(f);
  u += 0x7FFFu + ((u >> 16) & 1u);
  return (u16)(u >> 16);
}

// -------- f32 -> bf16 convert (all three inputs) + mask bitmap, one launch --
extern "C" __global__ __launch_bounds__(256) void cvt_all(
    const float* __restrict__ query, const float* __restrict__ w_in,
    const float* __restrict__ w_out, u16* __restrict__ dst,
    const unsigned char* __restrict__ mask, u64* __restrict__ mbits) {
  if (blockIdx.x == 12288) {
    // mask -> per-tile u64 bitmap: mbits[b*32+tile] bit j = mask[b][tile*64+j]
    const int i = threadIdx.x;
    if (i < 128) {
      const unsigned char* p = mask + i * 64;
      u64 bits = 0;
#pragma unroll
      for (int j = 0; j < 8; ++j) {
        const u64 c = *(const u64*)(p + j * 8);
#pragma unroll
        for (int bb = 0; bb < 8; ++bb)
          if ((c >> (8 * bb)) & 0xFFull) bits |= 1ull << (j * 8 + bb);
      }
      mbits[i] = bits;
    }
    return;
  }
  int i = (blockIdx.x * 256 + threadIdx.x) * 4;
  const float* src;
  int off;
  if (i < 8388608) {
    src = query; off = i;
  } else if (i < 11534336) {
    src = w_in; off = i - 8388608;
  } else {
    src = w_out; off = i - 11534336;
  }
  float4 v = *(const float4*)(src + off);
  ushort4 o;
  o.x = f2bf(v.x); o.y = f2bf(v.y); o.z = f2bf(v.z); o.w = f2bf(v.w);
  *(ushort4*)(dst + i) = o;
}

// ---------------- QKV projection GEMM (128x128, 2-buf, 1-ahead) ------------
// XCD-chunked swizzle; LDS-bounce epilogue -> coalesced q/k + direct v^T.
extern "C" __global__ __launch_bounds__(256) void gemm_qkv(
    const u16* __restrict__ X, const u16* __restrict__ W,
    const float* __restrict__ bias,
    u16* __restrict__ qb, u16* __restrict__ kb, u16* __restrict__ vtb) {
  const int tid = threadIdx.x;
  const int w = tid >> 6, lane = tid & 63;
  const int lg = lane >> 4, ll = lane & 15;
  const int wm = w >> 1, wn = w & 1;

  const int xcd = blockIdx.x & 7;
  const int i6 = blockIdx.x >> 3;        // 0..191
  const int tx = xcd * 8 + (i6 & 7);     // 0..63
  const int ty = i6 >> 3;                // 0..23
  const int row0A = tx * 128;
  const int row0B = ty * 128;

  __shared__ __align__(16) u16 SM[16384];  // 32 KB: staging dbuf, then epilogue
  u16* Asb = SM;          // [2][4096] u16 (8 KB per buf)
  u16* Bsb = SM + 8192;   // [2][4096]

  f32x4 acc[4][4] = {};

  const int r_st = tid >> 2;
  const int cb_st = (tid & 3) * 16;

#pragma unroll
  for (int it = 0; it < 2; ++it) {
    gl_lds16((const char*)X + ((size_t)(row0A + it * 64 + r_st) * 1024) * 2 + cb_st,
             (char*)Asb + it * 4096 + w * 1024);
    gl_lds16((const char*)W + ((size_t)(row0B + it * 64 + r_st) * 1024) * 2 + cb_st,
             (char*)Bsb + it * 4096 + w * 1024);
  }

  for (int kt = 0; kt < 32; ++kt) {
    const int cur = kt & 1;
    asm volatile("s_waitcnt vmcnt(0)" ::: "memory");
    __syncthreads();
    if (kt + 1 < 32) {
      const int k0 = (kt + 1) * 32;
      const int nxt = cur ^ 1;
#pragma unroll
      for (int it = 0; it < 2; ++it) {
        gl_lds16((const char*)X + ((size_t)(row0A + it * 64 + r_st) * 1024 + k0) * 2 + cb_st,
                 (char*)(Asb + nxt * 4096) + it * 4096 + w * 1024);
        gl_lds16((const char*)W + ((size_t)(row0B + it * 64 + r_st) * 1024 + k0) * 2 + cb_st,
                 (char*)(Bsb + nxt * 4096) + it * 4096 + w * 1024);
      }
    }
    const u16* Ab = Asb + cur * 4096;
    const u16* Bb = Bsb + cur * 4096;
    const int kc = lg * 8;
    bf16x8 a[4], bfr[4];
#pragma unroll
    for (int i = 0; i < 4; ++i)
      a[i] = *(const bf16x8*)(Ab + (wm * 64 + i * 16 + ll) * 32 + kc);
#pragma unroll
    for (int j = 0; j < 4; ++j)
      bfr[j] = *(const bf16x8*)(Bb + (wn * 64 + j * 16 + ll) * 32 + kc);
#pragma unroll
    for (int i = 0; i < 4; ++i)
#pragma unroll
      for (int j = 0; j < 4; ++j)
        acc[i][j] = __builtin_amdgcn_mfma_f32_16x16x32_bf16(a[i], bfr[j], acc[i][j], 0, 0, 0);
  }

  // ---- epilogue: bias+convert -> LDS [256 rows][64 u16] (XOR-swz 16B slots)
  __syncthreads();
  const int which = row0B >> 10;  // 0=q 1=k 2=v
  const float scl = which == 0 ? QSCALE : 1.0f;
  const int hh0 = (row0B & 1023) >> 6;

#pragma unroll
  for (int j = 0; j < 4; ++j) {
    const int n = row0B + wn * 64 + j * 16 + ll;
    const float bv = bias[n];
#pragma unroll
    for (int i = 0; i < 4; ++i)
#pragma unroll
      for (int r = 0; r < 4; ++r) {
        const float val = (acc[i][j][r] + bv) * scl;
        u16 pay;
        if (which == 2) {
          const f16 hv = (f16)val;
          pay = __builtin_bit_cast(u16, hv);
        } else {
          pay = f2bf(val);
        }
        const int lrow = wn * 128 + r * 32 + wm * 16 + i * 4 + lg;
        const int slot = (j * 2 + (ll >> 3)) ^ (lrow & 7);
        SM[lrow * 64 + slot * 8 + (ll & 7)] = pay;
      }
  }
  __syncthreads();

  if (which < 2) {
    u16* dst = which ? kb : qb;
    const int lrow = tid;
    const int hh = hh0 + (lrow >> 7);
    const int bb = (lrow >> 5) & 3;
    const int tt = (row0A >> 2) + (lrow & 31);
    u16* gp = dst + ((size_t)(bb * 16 + hh) * 2048 + tt) * 64;
#pragma unroll
    for (int s = 0; s < 8; ++s)
      *(u16x8*)(gp + s * 8) = *(const u16x8*)(SM + lrow * 64 + ((s ^ (lrow & 7)) << 3));
  } else {
#pragma unroll
    for (int u = 0; u < 2; ++u) {
      const int rid = u * 256 + tid;
      const int bb = rid >> 7, hhr = (rid >> 6) & 1, dd = rid & 63;
      const int hh = hh0 + hhr;
      const int slot0 = dd >> 3, de = dd & 7;
      u16 col[32];
#pragma unroll
      for (int t2 = 0; t2 < 32; ++t2) {
        const int lrow = hhr * 128 + bb * 32 + t2;
        col[t2] = SM[lrow * 64 + ((slot0 ^ (lrow & 7)) << 3) + de];
      }
      u16* gp = vtb + ((size_t)(bb * 16 + hh) * 64 + dd) * 2048 + (row0A >> 2);
#pragma unroll
      for (int sg = 0; sg < 4; ++sg)
        *(u16x8*)(gp + sg * 8) = *(const u16x8*)(col + sg * 8);
    }
  }
}

// ---------------- flash attention fwd (v6: f16 P, dot2 lsum) ----------------
extern "C" __global__ __launch_bounds__(256, 4) void flash_fwd(
    const u16* __restrict__ q, const u16* __restrict__ k,
    const u16* __restrict__ vt, const u64* __restrict__ mbits,
    u16* __restrict__ attn_pre, float* __restrict__ stat_il) {
  const int lb = ((blockIdx.x & 7) << 7) + (blockIdx.x >> 3);
  const int bh = lb >> 4, tt = lb & 15;
  const int b = bh >> 4, hd = bh & 15;
  const int t0 = tt * 128;
  const int tid = threadIdx.x, w = tid >> 6, lane = tid & 63;
  const int hl = lane >> 5;  // lane half (0/1)
  const int l31 = lane & 31;

  __shared__ __align__(16) u16 Ks[2][64 * 64];  // 16 KB bf16
  __shared__ __align__(16) u16 Vs[2][64 * 64];  // 16 KB f16

  const int qrow = t0 + w * 32 + l31;
  const u16* qp = q + ((size_t)bh * 2048 + qrow) * 64 + hl * 8;
  bf16x8 qreg[4];
#pragma unroll
  for (int kg = 0; kg < 4; ++kg) qreg[kg] = *(const bf16x8*)(qp + kg * 16);

  f32x16 po[2] = {};
  float ls0 = 0.f, ls1 = 0.f;
  const h16x2 ones = {(__fp16)1.0f, (__fp16)1.0f};

  const int slot_r = tid >> 3;
  const int slot_c8 = (tid & 7) ^ (slot_r & 7);

#define STAGE_F(buf, s0_)                                                      \
  do {                                                                         \
    _Pragma("unroll") for (int it2 = 0; it2 < 2; ++it2) {                      \
      const int rr = it2 * 32 + slot_r;                                        \
      gl_lds16((const char*)k +                                                \
                   (((size_t)bh * 2048 + (s0_) + rr) * 64 + slot_c8 * 8) * 2,  \
               (char*)&Ks[buf][0] + it2 * 4096 + w * 1024);                    \
      gl_lds16((const char*)vt +                                               \
                   (((size_t)bh * 64 + rr) * 2048 + (s0_) + slot_c8 * 8) * 2,  \
               (char*)&Vs[buf][0] + it2 * 4096 + w * 1024);                    \
    }                                                                          \
  } while (0)

  STAGE_F(0, 0);
  asm volatile("s_waitcnt vmcnt(0)" ::: "memory");
  __builtin_amdgcn_s_barrier();

  for (int t = 0; t < 32; ++t) {
    const u64 mb = mbits[b * 32 + t];  // uniform -> SGPR
    const int cur = t & 1;
    if (t + 1 < 32) STAGE_F(cur ^ 1, (t + 1) * 64);

    const char* Kb = (const char*)&Ks[cur][0];
    const char* Vb = (const char*)&Vs[cur][0];

#pragma unroll
    for (int kt = 0; kt < 2; ++kt) {
      f32x16 z = {};
      const int key = kt * 32 + l31;
      __builtin_amdgcn_s_setprio(1);
#pragma unroll
      for (int kg = 0; kg < 4; ++kg) {
        const bf16x8 kf = *(const bf16x8*)(
            Kb + key * 128 + ((((kg << 1) | hl) ^ (key & 7)) << 4));
        z = __builtin_amdgcn_mfma_f32_32x32x16_bf16(kf, qreg[kg], z, 0, 0, 0);
      }
      __builtin_amdgcn_s_setprio(0);

      float ps[16];
#pragma unroll
      for (int r = 0; r < 16; ++r) ps[r] = __builtin_amdgcn_exp2f(z[r]);
      const u32 m32 = (u32)(mb >> (kt * 32));
      if (m32) {
#pragma unroll
        for (int r = 0; r < 16; ++r) {
          const int bitpos = (r & 3) + 8 * (r >> 2) + 4 * hl;
          if ((m32 >> bitpos) & 1u) ps[r] = 0.f;
        }
      }

      u32 w8[8];
#pragma unroll
      for (int j = 0; j < 8; ++j) {
        const h16x2 pk = __builtin_amdgcn_cvt_pkrtz(ps[2 * j], ps[2 * j + 1]);
        w8[j] = __builtin_bit_cast(u32, pk);
        if (j & 1)
          ls1 = __builtin_amdgcn_fdot2(pk, ones, ls1, false);
        else
          ls0 = __builtin_amdgcn_fdot2(pk, ones, ls0, false);
      }

#pragma unroll
      for (int f = 0; f < 2; ++f) {
        u32 d0 = w8[4 * f], d1 = w8[4 * f + 1];
        u32 s0w = w8[4 * f + 2], s1w = w8[4 * f + 3];
        asm volatile("v_permlane32_swap_b32 %0, %1" : "+v"(d0), "+v"(s0w));
        asm volatile("v_permlane32_swap_b32 %0, %1" : "+v"(d1), "+v"(s1w));
        const f16x8 pa = __builtin_bit_cast(f16x8, (u32x4){d0, d1, s0w, s1w});
        const int g = kt * 2 + f;
        __builtin_amdgcn_s_setprio(1);
#pragma unroll
        for (int dt = 0; dt < 2; ++dt) {
          const int d = dt * 32 + l31;
          const f16x8 vf = *(const f16x8*)(
              Vb + d * 128 + ((((g << 1) | hl) ^ (d & 7)) << 4));
          po[dt] = __builtin_amdgcn_mfma_f32_32x32x16_f16(pa, vf, po[dt], 0, 0, 0);
        }
        __builtin_amdgcn_s_setprio(0);
      }
    }

    asm volatile("s_waitcnt vmcnt(0)" ::: "memory");
    __builtin_amdgcn_s_barrier();
  }

  float lsum = ls0 + ls1;
  lsum += __shfl_xor(lsum, 32, 64);
  const float linv = 1.0f / lsum;
  if (lane < 32)
    stat_il[(size_t)bh * 2048 + t0 + w * 32 + lane] = linv;

#pragma unroll
  for (int r = 0; r < 16; ++r) {
    const int qi = (r & 3) + 8 * (r >> 2) + 4 * hl;
    const float lv = __shfl(linv, qi, 64);
    const int trow = t0 + w * 32 + qi;
#pragma unroll
    for (int dt = 0; dt < 2; ++dt) {
      const int dd = dt * 32 + l31;
      attn_pre[((size_t)(trow * 4 + b)) * 1024 + hd * 64 + dd] =
          f2bf(po[dt][r] * lv);
    }
  }
#undef STAGE_F
}

// ------- fused tail: wavg (2048 blocks) + gemm_out (512 blocks), 4:1 -------
// Independent kernels co-scheduled in one dispatch so gemm_out's barrier
// drains overlap wavg's exp2 VALU work (and vice versa). Shared 48KB LDS.
extern "C" __global__ __launch_bounds__(256, 3) void tail_fused(
    const u16* __restrict__ q, const u16* __restrict__ k,
    const u64* __restrict__ mbits, const float* __restrict__ stat_il,
    float* __restrict__ wout,
    const u16* __restrict__ A, const u16* __restrict__ Wo,
    const float* __restrict__ bias, float* __restrict__ out) {
  __shared__ __align__(16) u16 POOL[24576];  // 48 KB
  const int bid = blockIdx.x;     // 2560 = 512 groups of {4 wavg, 1 gemm_out}
  const int g5 = bid / 5, r5 = bid % 5;
  const int tid = threadIdx.x, w = tid >> 6, lane = tid & 63;

  if (r5 == 4) {
    // ================= gemm_out block g5 (0..511) =================
    const int lg = lane >> 4, ll = lane & 15;
    const int wm = w >> 1, wn = w & 1;
    const int xcd = g5 & 7;
    const int i6 = g5 >> 3;
    const int row0A = (xcd * 8 + (i6 & 7)) * 128;
    const int row0B = (i6 >> 3) * 128;

    u16* Asb = POOL;          // [2][4096]
    u16* Bsb = POOL + 8192;   // [2][4096]

    f32x4 acc[4][4] = {};
    const int r_st = tid >> 2;
    const int cb_st = (tid & 3) * 16;

#pragma unroll
    for (int it = 0; it < 2; ++it) {
      gl_lds16((const char*)A + ((size_t)(row0A + it * 64 + r_st) * 1024) * 2 + cb_st,
               (char*)Asb + it * 4096 + w * 1024);
      gl_lds16((const char*)Wo + ((size_t)(row0B + it * 64 + r_st) * 1024) * 2 + cb_st,
               (char*)Bsb + it * 4096 + w * 1024);
    }

    for (int kt = 0; kt < 32; ++kt) {
      const int cur = kt & 1;
      asm volatile("s_waitcnt vmcnt(0)" ::: "memory");
      __syncthreads();
      if (kt + 1 < 32) {
        const int k0 = (kt + 1) * 32;
        const int nxt = cur ^ 1;
#pragma unroll
        for (int it = 0; it < 2; ++it) {
          gl_lds16((const char*)A + ((size_t)(row0A + it * 64 + r_st) * 1024 + k0) * 2 + cb_st,
                   (char*)(Asb + nxt * 4096) + it * 4096 + w * 1024);
          gl_lds16((const char*)Wo + ((size_t)(row0B + it * 64 + r_st) * 1024 + k0) * 2 + cb_st,
                   (char*)(Bsb + nxt * 4096) + it * 4096 + w * 1024);
        }
      }
      const u16* Ab = Asb + cur * 4096;
      const u16* Bb = Bsb + cur * 4096;
      const int kc = lg * 8;
      bf16x8 a[4], bfr[4];
#pragma unroll
      for (int i = 0; i < 4; ++i)
        a[i] = *(const bf16x8*)(Ab + (wm * 64 + i * 16 + ll) * 32 + kc);
#pragma unroll
      for (int j = 0; j < 4; ++j)
        bfr[j] = *(const bf16x8*)(Bb + (wn * 64 + j * 16 + ll) * 32 + kc);
#pragma unroll
      for (int i = 0; i < 4; ++i)
#pragma unroll
        for (int j = 0; j < 4; ++j)
          acc[i][j] = __builtin_amdgcn_mfma_f32_16x16x32_bf16(a[i], bfr[j], acc[i][j], 0, 0, 0);
    }

#pragma unroll
    for (int j = 0; j < 4; ++j) {
      const int n = row0B + wn * 64 + j * 16 + ll;
      const float bv = bias[n];
#pragma unroll
      for (int i = 0; i < 4; ++i)
#pragma unroll
        for (int r = 0; r < 4; ++r) {
          const int m = row0A + wm * 64 + i * 16 + lg * 4 + r;
          out[(size_t)m * 1024 + n] = acc[i][j][r] + bv;
        }
    }
    return;
  }

  // ================= wavg block wb (0..2047) =================
  const int wb = g5 * 4 + r5;
  const int lb = ((wb & 7) << 8) + (wb >> 3);  // XCD-chunked swizzle
  const int b = lb >> 9, tt = (lb >> 5) & 15, st = lb & 31;
  const int t0 = tt * 128, s0 = st * 64;
  const int hl = lane >> 5;
  const int l31 = lane & 31;

  // Qs[buf] = POOL + buf*8192 (32 KB); Ks2[buf] = POOL+16384 + buf*4096 (16 KB)
  const int slot_r8 = tid >> 3;
  const int slot_c8 = (tid & 7) ^ (slot_r8 & 7);

  const u64 mbw = mbits[b * 32 + st];  // uniform
  const u32 m32lo = (u32)mbw, m32hi = (u32)(mbw >> 32);
  const bool domask = mbw != 0ull;

#define STAGE_W(buf, hh)                                                       \
  do {                                                                         \
    const size_t qo_ = (size_t)(b * 16 + (hh)) * 2048;                         \
    _Pragma("unroll") for (int i2 = 0; i2 < 4; ++i2) {                         \
      const int rr = i2 * 32 + slot_r8;                                        \
      gl_lds16((const char*)q + ((qo_ + t0 + rr) * 64 + slot_c8 * 8) * 2,      \
               (char*)(POOL + (buf)*8192) + i2 * 4096 + w * 1024);             \
    }                                                                          \
    _Pragma("unroll") for (int i2 = 0; i2 < 2; ++i2) {                         \
      const int rr = i2 * 32 + slot_r8;                                        \
      gl_lds16((const char*)k + ((qo_ + s0 + rr) * 64 + slot_c8 * 8) * 2,      \
               (char*)(POOL + 16384 + (buf)*4096) + i2 * 4096 + w * 1024);     \
    }                                                                          \
  } while (0)

  STAGE_W(0, 0);
  asm volatile("s_waitcnt vmcnt(0)" ::: "memory");
  __syncthreads();

  float accw[32] = {};
  for (int h = 0; h < 16; ++h) {
    const int cur = h & 1;
    const float ilh =
        stat_il[(size_t)(b * 16 + h) * 2048 + t0 + w * 32 + l31];

    if (h + 1 < 16) STAGE_W(cur ^ 1, h + 1);

    const char* Qb = (const char*)(POOL + cur * 8192);
    const char* Kb = (const char*)(POOL + 16384 + cur * 4096);

    const int qr = w * 32 + l31;
    bf16x8 qf[4];
#pragma unroll
    for (int kg = 0; kg < 4; ++kg)
      qf[kg] = *(const bf16x8*)(
          Qb + qr * 128 + ((((kg << 1) | hl) ^ (qr & 7)) << 4));

    f32x16 z0 = {}, z1 = {};
    __builtin_amdgcn_s_setprio(1);
#pragma unroll
    for (int kg = 0; kg < 4; ++kg) {
      const int key = l31;
      const bf16x8 kf = *(const bf16x8*)(
          Kb + key * 128 + ((((kg << 1) | hl) ^ (key & 7)) << 4));
      z0 = __builtin_amdgcn_mfma_f32_32x32x16_bf16(kf, qf[kg], z0, 0, 0, 0);
    }
#pragma unroll
    for (int kg = 0; kg < 4; ++kg) {
      const int key = 32 + l31;
      const bf16x8 kf = *(const bf16x8*)(
          Kb + key * 128 + ((((kg << 1) | hl) ^ (key & 7)) << 4));
      z1 = __builtin_amdgcn_mfma_f32_32x32x16_bf16(kf, qf[kg], z1, 0, 0, 0);
    }
    __builtin_amdgcn_s_setprio(0);

#pragma unroll
    for (int r = 0; r < 16; ++r) {
      float p = __builtin_amdgcn_exp2f(z0[r]);
      if (domask) {
        const int bitpos = (r & 3) + 8 * (r >> 2) + 4 * hl;
        if ((m32lo >> bitpos) & 1u) p = 0.f;
      }
      accw[r] = fmaf(p, ilh, accw[r]);
    }
#pragma unroll
    for (int r = 0; r < 16; ++r) {
      float p = __builtin_amdgcn_exp2f(z1[r]);
      if (domask) {
        const int bitpos = (r & 3) + 8 * (r >> 2) + 4 * hl;
        if ((m32hi >> bitpos) & 1u) p = 0.f;
      }
      accw[16 + r] = fmaf(p, ilh, accw[16 + r]);
    }

    asm volatile("s_waitcnt vmcnt(0)" ::: "memory");
    __syncthreads();
  }

  // transpose via LDS (8 KB per wave) then coalesced f32x4 writes
  float* tb = ((float*)POOL) + w * 2048;
#pragma unroll
  for (int kt = 0; kt < 2; ++kt)
#pragma unroll
    for (int j = 0; j < 4; ++j) {
      f32x4 qd;
#pragma unroll
      for (int e = 0; e < 4; ++e) qd[e] = accw[kt * 16 + 4 * j + e] * 0.0625f;
      const int slot = kt * 8 + 2 * j + hl;  // 16B slot within 256B row
      *(f32x4*)(tb + l31 * 64 + ((slot ^ (l31 & 7)) << 2)) = qd;
    }
  __syncthreads();
#pragma unroll
  for (int j2 = 0; j2 < 8; ++j2) {
    const int row = j2 * 4 + (lane >> 4);
    const int slot = lane & 15;
    const f32x4 v = *(const f32x4*)(tb + row * 64 + ((slot ^ (row & 7)) << 2));
    *(f32x4*)(wout + ((size_t)b * 2048 + t0 + w * 32 + row) * 2048 + s0 +
              slot * 4) = v;
  }
#undef STAGE_W
}

extern "C" void kernel_launch(void* const* d_in, const int* in_sizes, int n_in,
                              void* d_out, int out_size, void* d_ws, size_t ws_size,
                              hipStream_t stream) {
  const float* query = (const float*)d_in[0];
  const unsigned char* mask = (const unsigned char*)d_in[1];
  const float* w_in = (const float*)d_in[2];
  const float* b_in = (const float*)d_in[3];
  const float* w_out = (const float*)d_in[4];
  const float* b_out = (const float*)d_in[5];

  float* out0 = (float*)d_out;                   // attn [T,B,E] = 8388608 f32
  float* outw = out0 + (size_t)8388608;          // attn_w_avg [B,T,S]

  char* ws = (char*)d_ws;
  u16* Xbf   = (u16*)(ws + 0);            // 16 MB  query bf16 [8192][1024]
  u16* Wqkv  = (u16*)(ws + 16777216);     // 6 MB   in_proj_weight bf16
  u16* Woutb = (u16*)(ws + 23068672);     // 2 MB   out_w bf16
  u16* qb    = (u16*)(ws + 25165824);     // 16 MB  q [B,H,T,D] bf16 (scaled)
  u16* kb    = (u16*)(ws + 41943040);     // 16 MB  k [B,H,T,D]
  u16* vtb   = (u16*)(ws + 75497472);     // 16 MB  v^T [B,H,D,T] f16
  u16* ap    = (u16*)(ws + 92274688);     // 16 MB  attn_pre bf16 [8192][1024]
  float* sil = (float*)(ws + 109051904);  // 0.5 MB row 1/l [B*H][T]
  u64* mbits = (u64*)(ws + 109576192);    // 1 KB   mask bitmap [B][32]

  cvt_all<<<12289, 256, 0, stream>>>(query, w_in, w_out, Xbf, mask, mbits);
  gemm_qkv<<<1536, 256, 0, stream>>>(Xbf, Wqkv, b_in, qb, kb, vtb);
  flash_fwd<<<1024, 256, 0, stream>>>(qb, kb, vtb, mbits, ap, sil);
  tail_fused<<<2560, 256, 0, stream>>>(qb, kb, mbits, sil, outw,
                                       ap, Woutb, b_out, out0);
}